// Round 1
// baseline (1778.930 us; speedup 1.0000x reference)
//
#include <hip/hip_runtime.h>

#define NTHREADS 256
#define NB 4        // nodes per block
#define K 16
#define KP1 17
#define F 128
#define H 8
#define D 64
#define FP 132      // padded row stride for xall: 132 % 32 = 4 -> k-rows hit distinct banks; 528B keeps 16B alignment
#define NEG_SLOPE 0.2f

__global__ __launch_bounds__(NTHREADS) void gat_kernel(
    const float* __restrict__ x_self,   // [N,F]
    const float* __restrict__ x_neigh,  // [N,K,F]
    const float* __restrict__ W,        // [H,F,D]
    const float* __restrict__ a_self,   // [H,F]
    const float* __restrict__ a_neigh,  // [H,F]
    float* __restrict__ out,            // [N,H*D]
    int N)
{
    __shared__ __align__(16) float xall[NB][KP1][FP];   // k=0 is self row
    __shared__ __align__(16) float attn[NB][KP1][H];
    __shared__ __align__(16) float yb[NB][H][F];        // unpadded: stride-1 writes, broadcast reads
    __shared__ float logit_self_s[NB][H];

    const int tid = threadIdx.x;
    const int node0 = blockIdx.x * NB;

    // ---- Phase 1: stage x_all into LDS (float4, coalesced) ----
    {
        const int tot_self = NB * (F / 4);              // 128 float4
        for (int i = tid; i < tot_self; i += NTHREADS) {
            int nb = i / (F / 4);
            int f4 = i % (F / 4);
            if (node0 + nb < N) {
                float4 v = ((const float4*)(x_self + (size_t)(node0 + nb) * F))[f4];
                *(float4*)&xall[nb][0][f4 * 4] = v;
            }
        }
        const int tot_n = NB * K * (F / 4);             // 2048 float4
        for (int i = tid; i < tot_n; i += NTHREADS) {
            int nb  = i / (K * F / 4);
            int rem = i % (K * F / 4);
            int k   = rem / (F / 4);
            int f4  = rem % (F / 4);
            if (node0 + nb < N) {
                float4 v = ((const float4*)(x_neigh + ((size_t)(node0 + nb) * K + k) * F))[f4];
                *(float4*)&xall[nb][k + 1][f4 * 4] = v;
            }
        }
    }
    __syncthreads();

    // ---- Phase 2a: self logits (32 tasks) ----
    for (int i = tid; i < NB * H; i += NTHREADS) {
        int nb = i / H, h = i % H;
        if (node0 + nb < N) {
            const float4* a4 = (const float4*)(a_self + h * F);
            float4 s = {0.f, 0.f, 0.f, 0.f};
            #pragma unroll
            for (int f4 = 0; f4 < F / 4; f4++) {
                float4 xv = *(const float4*)&xall[nb][0][f4 * 4];
                float4 av = a4[f4];
                s.x += xv.x * av.x; s.y += xv.y * av.y;
                s.z += xv.z * av.z; s.w += xv.w * av.w;
            }
            logit_self_s[nb][h] = (s.x + s.y) + (s.z + s.w);
        }
    }
    __syncthreads();

    // ---- Phase 2b: all logits + LeakyReLU (544 tasks) ----
    for (int i = tid; i < NB * KP1 * H; i += NTHREADS) {
        int nb  = i / (KP1 * H);
        int rem = i % (KP1 * H);
        int k   = rem / H, h = rem % H;
        if (node0 + nb < N) {
            const float4* a4 = (const float4*)(a_neigh + h * F);
            float4 s = {0.f, 0.f, 0.f, 0.f};
            #pragma unroll
            for (int f4 = 0; f4 < F / 4; f4++) {
                float4 xv = *(const float4*)&xall[nb][k][f4 * 4];
                float4 av = a4[f4];
                s.x += xv.x * av.x; s.y += xv.y * av.y;
                s.z += xv.z * av.z; s.w += xv.w * av.w;
            }
            float lg = logit_self_s[nb][h] + (s.x + s.y) + (s.z + s.w);
            lg = (lg >= 0.f) ? lg : NEG_SLOPE * lg;
            attn[nb][k][h] = lg;
        }
    }
    __syncthreads();

    // ---- Phase 3: softmax over k (32 tasks) ----
    for (int i = tid; i < NB * H; i += NTHREADS) {
        int nb = i / H, h = i % H;
        if (node0 + nb < N) {
            float m = -1e30f;
            #pragma unroll
            for (int k = 0; k < KP1; k++) m = fmaxf(m, attn[nb][k][h]);
            float s = 0.f;
            #pragma unroll
            for (int k = 0; k < KP1; k++) {
                float e = __expf(attn[nb][k][h] - m);
                attn[nb][k][h] = e;
                s += e;
            }
            float inv = 1.0f / s;
            #pragma unroll
            for (int k = 0; k < KP1; k++) attn[nb][k][h] *= inv;
        }
    }
    __syncthreads();

    // ---- Phase 4: y[nb][h][f] = sum_k attn * x_all (1024 float4 tasks) ----
    for (int i = tid; i < NB * H * (F / 4); i += NTHREADS) {
        int nb  = i / (H * F / 4);
        int rem = i % (H * F / 4);
        int h   = rem / (F / 4), f4 = rem % (F / 4);
        if (node0 + nb < N) {
            float4 s = {0.f, 0.f, 0.f, 0.f};
            #pragma unroll
            for (int k = 0; k < KP1; k++) {
                float a = attn[nb][k][h];
                float4 xv = *(const float4*)&xall[nb][k][f4 * 4];
                s.x += a * xv.x; s.y += a * xv.y;
                s.z += a * xv.z; s.w += a * xv.w;
            }
            *(float4*)&yb[nb][h][f4 * 4] = s;
        }
    }
    __syncthreads();

    // ---- Phase 5: out[nb][h][d] = y[nb][h][:] @ W[h][:][d] ----
    // tid -> d (0..63), head group (0..3); 2 heads x 4 nodes per thread.
    {
        const int d  = tid & (D - 1);
        const int hg = tid >> 6;         // 0..3
        #pragma unroll
        for (int hh = 0; hh < 2; hh++) {
            const int h = hg + 4 * hh;
            const float* Wp = W + ((size_t)h * F) * D + d;
            float acc[NB] = {0.f, 0.f, 0.f, 0.f};
            for (int f4 = 0; f4 < F / 4; f4++) {
                float w0 = Wp[(f4 * 4 + 0) * D];
                float w1 = Wp[(f4 * 4 + 1) * D];
                float w2 = Wp[(f4 * 4 + 2) * D];
                float w3 = Wp[(f4 * 4 + 3) * D];
                #pragma unroll
                for (int nb = 0; nb < NB; nb++) {
                    float4 yv = *(const float4*)&yb[nb][h][f4 * 4];
                    acc[nb] += yv.x * w0 + yv.y * w1 + yv.z * w2 + yv.w * w3;
                }
            }
            #pragma unroll
            for (int nb = 0; nb < NB; nb++) {
                if (node0 + nb < N) {
                    out[(size_t)(node0 + nb) * (H * D) + h * D + d] = acc[nb];
                }
            }
        }
    }
}

extern "C" void kernel_launch(void* const* d_in, const int* in_sizes, int n_in,
                              void* d_out, int out_size, void* d_ws, size_t ws_size,
                              hipStream_t stream) {
    const float* x_self  = (const float*)d_in[0];
    const float* x_neigh = (const float*)d_in[1];
    const float* W       = (const float*)d_in[2];
    const float* a_self  = (const float*)d_in[3];
    const float* a_neigh = (const float*)d_in[4];
    float* out = (float*)d_out;

    const int N = in_sizes[0] / F;                 // 50000
    const int nblocks = (N + NB - 1) / NB;         // 12500
    gat_kernel<<<nblocks, NTHREADS, 0, stream>>>(x_self, x_neigh, W, a_self, a_neigh, out, N);
}

// Round 2
// 997.412 us; speedup vs baseline: 1.7835x; 1.7835x over previous
//
#include <hip/hip_runtime.h>

#define NTHREADS 256
#define NB 4        // nodes per block (N=50000 -> 12500 blocks, no tail)
#define K 16
#define KP1 17
#define F 128
#define H 8
#define D 64
#define FP 132      // padded xall row stride: rows land 4 banks apart; k,k+8 alias = 2-way (free)
#define NEG_SLOPE 0.2f

// LDS: xall 4*17*132*4 = 35904 + attn 4*17*8*4 = 2176 + self 128 = 38208 B -> 4 blocks/CU
// VGPR: __launch_bounds__(256,4) -> <=128 VGPR (4 waves/SIMD, 16 waves/CU)

__global__ __launch_bounds__(NTHREADS, 4) void gat_kernel(
    const float* __restrict__ x_self,   // [N,F]
    const float* __restrict__ x_neigh,  // [N,K,F]
    const float* __restrict__ W,        // [H,F,D]
    const float* __restrict__ a_self,   // [H,F]
    const float* __restrict__ a_neigh,  // [H,F]
    float* __restrict__ out,            // [N,H*D]
    int N)
{
    __shared__ __align__(16) float xall[NB][KP1][FP];   // k=0 is self row; reused as yb after phase 4
    __shared__ __align__(16) float attn[NB][KP1][H];
    __shared__ float self_s[NB][H];

    float* yb = (float*)xall;   // [NB][H][F] alias, valid after phase-4 second sync

    const int tid = threadIdx.x;
    const int node0 = blockIdx.x * NB;

    // ---- Phase 1: stage x_all into LDS (float4, coalesced) ----
    {
        const int tot_self = NB * (F / 4);              // 128 float4
        for (int i = tid; i < tot_self; i += NTHREADS) {
            int nb = i / (F / 4);
            int f4 = i % (F / 4);
            if (node0 + nb < N) {
                float4 v = ((const float4*)(x_self + (size_t)(node0 + nb) * F))[f4];
                *(float4*)&xall[nb][0][f4 * 4] = v;
            }
        }
        const int tot_n = NB * K * (F / 4);             // 2048 float4
        for (int i = tid; i < tot_n; i += NTHREADS) {
            int nb  = i / (K * F / 4);
            int rem = i % (K * F / 4);
            int k   = rem / (F / 4);
            int f4  = rem % (F / 4);
            if (node0 + nb < N) {
                float4 v = ((const float4*)(x_neigh + ((size_t)(node0 + nb) * K + k) * F))[f4];
                *(float4*)&xall[nb][k + 1][f4 * 4] = v;
            }
        }
    }
    __syncthreads();

    // ---- Phase 2: unified logit dots. 576 tasks = NB * (17*8 neigh-dots + 8 self-dots) ----
    {
        const int TPN = KP1 * H + H;                    // 144 tasks per node
        for (int i = tid; i < NB * TPN; i += NTHREADS) {
            int nb  = i / TPN;
            int rem = i % TPN;
            int k, h;
            const float* av;
            const float* xr;
            bool is_self = (rem >= KP1 * H);
            if (!is_self) {
                k = rem >> 3; h = rem & 7;
                av = a_neigh + h * F;
                xr = &xall[nb][k][0];
            } else {
                k = 0; h = rem - KP1 * H;
                av = a_self + h * F;
                xr = &xall[nb][0][0];
            }
            float4 s = {0.f, 0.f, 0.f, 0.f};
            #pragma unroll 8
            for (int f4 = 0; f4 < F / 4; f4++) {
                float4 xv = *(const float4*)(xr + f4 * 4);
                float4 avv = ((const float4*)av)[f4];
                s.x += xv.x * avv.x; s.y += xv.y * avv.y;
                s.z += xv.z * avv.z; s.w += xv.w * avv.w;
            }
            float dot = (s.x + s.y) + (s.z + s.w);
            if (!is_self) attn[nb][k][h] = dot;
            else          self_s[nb][h] = dot;
        }
    }
    __syncthreads();

    // ---- Phase 3: add self logit, LeakyReLU, softmax over k (32 tasks) ----
    for (int i = tid; i < NB * H; i += NTHREADS) {
        int nb = i >> 3, h = i & 7;
        float sl = self_s[nb][h];
        float m = -1e30f;
        #pragma unroll
        for (int k = 0; k < KP1; k++) {
            float lg = sl + attn[nb][k][h];
            lg = (lg >= 0.f) ? lg : NEG_SLOPE * lg;
            attn[nb][k][h] = lg;
            m = fmaxf(m, lg);
        }
        float s = 0.f;
        #pragma unroll
        for (int k = 0; k < KP1; k++) {
            float e = __expf(attn[nb][k][h] - m);
            attn[nb][k][h] = e;
            s += e;
        }
        float inv = 1.0f / s;
        #pragma unroll
        for (int k = 0; k < KP1; k++) attn[nb][k][h] *= inv;
    }
    __syncthreads();

    // ---- Phase 4: y[nb][h][f] = sum_k attn * x_all, accumulated in registers,
    //      then written into the (now dead) xall storage. ----
    {
        const int h  = (tid >> 5) & 7;   // 0..7
        const int f4 = tid & 31;         // 0..31
        float4 acc[NB];
        #pragma unroll
        for (int j = 0; j < NB; j++) acc[j] = {0.f, 0.f, 0.f, 0.f};
        for (int k = 0; k < KP1; k++) {
            #pragma unroll
            for (int j = 0; j < NB; j++) {
                float a = attn[j][k][h];
                float4 xv = *(const float4*)&xall[j][k][f4 * 4];
                acc[j].x += a * xv.x; acc[j].y += a * xv.y;
                acc[j].z += a * xv.z; acc[j].w += a * xv.w;
            }
        }
        __syncthreads();   // everyone done READING xall
        #pragma unroll
        for (int j = 0; j < NB; j++) {
            *(float4*)&yb[((size_t)j * H + h) * F + f4 * 4] = acc[j];
        }
    }
    __syncthreads();

    // ---- Phase 5: out[nb][h][d] = y[nb][h][:] @ W[h][:][d] ----
    // tid -> d (0..63), head group (0..3); 2 heads x 4 nodes per thread.
    {
        const int d  = tid & (D - 1);
        const int hg = tid >> 6;         // wave id = head group; all lanes share h -> yb reads broadcast
        #pragma unroll
        for (int hh = 0; hh < 2; hh++) {
            const int h = hg + 4 * hh;
            const float* Wp = W + ((size_t)h * F) * D + d;
            float acc[NB] = {0.f, 0.f, 0.f, 0.f};
            #pragma unroll 4
            for (int f4 = 0; f4 < F / 4; f4++) {
                float w0 = Wp[(f4 * 4 + 0) * D];
                float w1 = Wp[(f4 * 4 + 1) * D];
                float w2 = Wp[(f4 * 4 + 2) * D];
                float w3 = Wp[(f4 * 4 + 3) * D];
                #pragma unroll
                for (int nb = 0; nb < NB; nb++) {
                    float4 yv = *(const float4*)&yb[((size_t)nb * H + h) * F + f4 * 4];
                    acc[nb] += yv.x * w0 + yv.y * w1 + yv.z * w2 + yv.w * w3;
                }
            }
            #pragma unroll
            for (int nb = 0; nb < NB; nb++) {
                if (node0 + nb < N) {
                    out[(size_t)(node0 + nb) * (H * D) + h * D + d] = acc[nb];
                }
            }
        }
    }
}

extern "C" void kernel_launch(void* const* d_in, const int* in_sizes, int n_in,
                              void* d_out, int out_size, void* d_ws, size_t ws_size,
                              hipStream_t stream) {
    const float* x_self  = (const float*)d_in[0];
    const float* x_neigh = (const float*)d_in[1];
    const float* W       = (const float*)d_in[2];
    const float* a_self  = (const float*)d_in[3];
    const float* a_neigh = (const float*)d_in[4];
    float* out = (float*)d_out;

    const int N = in_sizes[0] / F;                 // 50000
    const int nblocks = (N + NB - 1) / NB;         // 12500
    gat_kernel<<<nblocks, NTHREADS, 0, stream>>>(x_self, x_neigh, W, a_self, a_neigh, out, N);
}